// Round 6
// baseline (780.856 us; speedup 1.0000x reference)
//
#include <hip/hip_runtime.h>

#define BB 32
#define TT 8
#define NN 1024
#define KNN 20
#define HH 64
#define CLS 14

__device__ __constant__ float kEPS = 1e-5f;

// order-preserving flip: float bits -> uint with same total order
__device__ __forceinline__ unsigned flipbits(unsigned u) {
    return u ^ ((unsigned)((int)u >> 31) | 0x80000000u);
}
// inverse of flipbits
__device__ __forceinline__ float unflip(unsigned fu) {
    const unsigned u = (fu & 0x80000000u) ? (fu ^ 0x80000000u) : ~fu;
    return __uint_as_float(u);
}
__device__ __forceinline__ int mbcnt64(unsigned long long m) {
    return (int)__builtin_amdgcn_mbcnt_hi((unsigned)(m >> 32),
            __builtin_amdgcn_mbcnt_lo((unsigned)m, 0u));
}

// Exact iterative extraction fallback (survivor overflow only; cold).
__device__ __forceinline__ void fallback20(unsigned fd[16], int lane, unsigned* nb) {
    for (int kk = 0; kk < KNN; ++kk) {
        unsigned bv = fd[0];
        int bi = 0;
        #pragma unroll
        for (int i = 1; i < 16; ++i)
            if (fd[i] < bv) { bv = fd[i]; bi = i; }
        unsigned bj = (unsigned)(bi * 64 + lane);
        #pragma unroll
        for (int off = 32; off >= 1; off >>= 1) {
            const unsigned ov = __shfl_xor(bv, off, 64);
            const unsigned oj = __shfl_xor(bj, off, 64);
            if (ov < bv || (ov == bv && oj < bj)) { bv = ov; bj = oj; }
        }
        if (lane == 0) nb[kk] = bj;
        #pragma unroll
        for (int i = 0; i < 16; ++i)
            if (bj == (unsigned)(i * 64 + lane)) fd[i] = 0xFFFFFFFFu;
    }
}

// ---------------------------------------------------------------------------
// Kernel A: per (t, b, 64-point chunk). One wave = 16 query points, processed
// 2 at a time for ILP on the serial ballot chains — but with NO per-candidate
// register arrays (distances recomputed from LDS in pass 2), keeping VGPR low
// so occupancy stays high (R4/R5 lesson: occupancy > everything here).
// Per point pair:
//   pass1: per-lane min over 16 candidates each (no array)
//   12-step interleaved ballot radix on flipped lane-mins -> UB >= d(20)
//   pass2: recompute d, ballot-compact survivors (<=~24) into LDS keys
//   32-step interleaved ballot radix over survivor lanes -> exact v20
//   exact jax top-20 set ({<v20} U lowest-index ties) -> nbuf
//   EdgeConv with deferred ReLU/BN (sign-corrected weights, zmax only),
//   nbuf read as 5 packed uint4 per point.
// Epilogue: relu/scale/bias/clamp once, uint atomicMax into acc.
// ---------------------------------------------------------------------------
__global__ __launch_bounds__(256) void knn_edge_kernel(
    const float* __restrict__ x,    // [B,T,N,3]
    const float* __restrict__ W1,   // [6,H]
    const float* __restrict__ b1,   // [H]
    const float* __restrict__ g1,   // [H]
    const float* __restrict__ be1,  // [H]
    float* __restrict__ acc)        // [B, 7*H], zero-initialized
{
    __shared__ float4 pts[NN];                         // x, y, z, |p|^2
    __shared__ unsigned long long keybuf[4][2][64];    // per-wave, per-point
    __shared__ unsigned nbuf[4][2][KNN];               // selected neighbor idx
    __shared__ unsigned smax[HH];

    const int chunk = blockIdx.x;   // 0..15
    const int b     = blockIdx.y;   // 0..31
    const int t     = blockIdx.z;   // 0..6

    const int tid  = threadIdx.x;
    const int lane = tid & 63;
    const int wave = tid >> 6;

    for (int i = tid; i < NN; i += 256) {
        const float* p = x + (((size_t)b * TT + t) * NN + i) * 3;
        const float px = p[0], py = p[1], pz = p[2];
        pts[i] = make_float4(px, py, pz, px * px + py * py + pz * pz);
    }
    if (tid < HH) smax[tid] = 0u;
    __syncthreads();

    const float w3 = W1[3 * HH + lane], w4 = W1[4 * HH + lane],
                w5 = W1[5 * HH + lane];
    const float b1l   = b1[lane];
    const float scale = g1[lane] / sqrtf(1.0f + kEPS);
    const float be1l  = be1[lane];
    const float sgn = (scale >= 0.0f) ? 1.0f : -1.0f;
    const float w03 = sgn * (W1[0 * HH + lane] - w3),
                w14 = sgn * (W1[1 * HH + lane] - w4),
                w25 = sgn * (W1[2 * HH + lane] - w5);

    float zmax = -3.0e38f;

    const int n0 = chunk * 64 + wave * 16;
    for (int pp2 = 0; pp2 < 8; ++pp2) {
        const int nA = n0 + 2 * pp2;
        const float* c = x + (((size_t)b * TT + (t + 1)) * NN + nA) * 3;
        const float cxA = c[0], cyA = c[1], czA = c[2];
        const float cxB = c[3], cyB = c[4], czB = c[5];
        const float s1A = cxA * cxA + cyA * cyA + czA * czA;
        const float s1B = cxB * cxB + cyB * cyB + czB * czB;
        const float n2xA = -2.0f * cxA, n2yA = -2.0f * cyA, n2zA = -2.0f * czA;
        const float n2xB = -2.0f * cxB, n2yB = -2.0f * cyB, n2zB = -2.0f * czB;

        // pass 1: per-lane min only (no arrays -> low VGPR)
        float mnfA = 3.0e38f, mnfB = 3.0e38f;
        #pragma unroll
        for (int i = 0; i < 16; ++i) {
            const float4 q = pts[i * 64 + lane];
            const float dA = fmaf(n2xA, q.x, fmaf(n2yA, q.y, fmaf(n2zA, q.z, s1A + q.w)));
            const float dB = fmaf(n2xB, q.x, fmaf(n2yB, q.y, fmaf(n2zB, q.z, s1B + q.w)));
            mnfA = fminf(mnfA, dA);
            mnfB = fminf(mnfB, dB);
        }
        const unsigned mnA = flipbits(__float_as_uint(mnfA));
        const unsigned mnB = flipbits(__float_as_uint(mnfB));

        // 12-step interleaved ballot radix: UB >= 20th lane-min >= d(20)
        unsigned pA = 0, pB = 0;
        int kA = 19, kB = 19;
        #pragma unroll
        for (int bit = 31; bit >= 20; --bit) {
            const unsigned long long zA = __ballot(((mnA ^ pA) >> bit) == 0u);
            const unsigned long long zB = __ballot(((mnB ^ pB) >> bit) == 0u);
            const int cA0 = (int)__popcll(zA);
            const int cB0 = (int)__popcll(zB);
            if (kA >= cA0) { pA |= (1u << bit); kA -= cA0; }
            if (kB >= cB0) { pB |= (1u << bit); kB -= cB0; }
        }
        const float ubfA = unflip(pA | 0xFFFFFu);
        const float ubfB = unflip(pB | 0xFFFFFu);

        // pass 2: recompute distances, ballot-compact survivors
        int baseA = 0, baseB = 0;
        #pragma unroll
        for (int i = 0; i < 16; ++i) {
            const float4 q = pts[i * 64 + lane];
            const float dA = fmaf(n2xA, q.x, fmaf(n2yA, q.y, fmaf(n2zA, q.z, s1A + q.w)));
            const float dB = fmaf(n2xB, q.x, fmaf(n2yB, q.y, fmaf(n2zB, q.z, s1B + q.w)));
            const bool prA = dA <= ubfA;
            const bool prB = dB <= ubfB;
            const unsigned long long mA = __ballot(prA);
            const unsigned long long mB = __ballot(prB);
            if (prA) {
                const int pos = baseA + mbcnt64(mA);
                if (pos < 64) keybuf[wave][0][pos] =
                    ((unsigned long long)__float_as_uint(dA) << 32)
                    | (unsigned)(i * 64 + lane);
            }
            if (prB) {
                const int pos = baseB + mbcnt64(mB);
                if (pos < 64) keybuf[wave][1][pos] =
                    ((unsigned long long)__float_as_uint(dB) << 32)
                    | (unsigned)(i * 64 + lane);
            }
            baseA += (int)__popcll(mA);
            baseB += (int)__popcll(mB);
        }

        if (baseA <= 64 && baseB <= 64) {
            const unsigned long long keyA = keybuf[wave][0][lane];
            const unsigned long long keyB = keybuf[wave][1][lane];
            const bool vA = lane < baseA, vB = lane < baseB;
            const unsigned sfdA = vA ? flipbits((unsigned)(keyA >> 32)) : 0xFFFFFFFFu;
            const unsigned sfdB = vB ? flipbits((unsigned)(keyB >> 32)) : 0xFFFFFFFFu;
            const unsigned sidxA = (unsigned)keyA & 1023u;
            const unsigned sidxB = (unsigned)keyB & 1023u;

            // 32-step interleaved radix-select: exact rank-19 value
            unsigned v20A = 0, v20B = 0;
            int k2A = 19, k2B = 19;
            #pragma unroll
            for (int bit = 31; bit >= 0; --bit) {
                const unsigned long long zA = __ballot(vA && ((sfdA ^ v20A) >> bit) == 0u);
                const unsigned long long zB = __ballot(vB && ((sfdB ^ v20B) >> bit) == 0u);
                const int cA0 = (int)__popcll(zA);
                const int cB0 = (int)__popcll(zB);
                if (k2A >= cA0) { v20A |= (1u << bit); k2A -= cA0; }
                if (k2B >= cB0) { v20B |= (1u << bit); k2B -= cB0; }
            }

            // exact top-20 set A: {fd < v20} U lowest-index ties at v20
            {
                const unsigned long long ltm = __ballot(vA && sfdA < v20A);
                const int need = KNN - (int)__popcll(ltm);
                const unsigned long long tiedm = __ballot(vA && sfdA == v20A);
                bool sel;
                if ((int)__popcll(tiedm) == need) {
                    sel = vA && sfdA <= v20A;
                } else {
                    int r = 0;
                    unsigned long long mm = tiedm;
                    while (mm) {
                        const int l = __builtin_ctzll(mm);
                        const unsigned oi = __shfl(sidxA, l, 64);
                        r += (oi < sidxA) ? 1 : 0;
                        mm &= mm - 1;
                    }
                    sel = vA && (sfdA < v20A || (sfdA == v20A && r < need));
                }
                const unsigned long long sm = __ballot(sel);
                if (sel) nbuf[wave][0][mbcnt64(sm)] = sidxA;
            }
            // exact top-20 set B
            {
                const unsigned long long ltm = __ballot(vB && sfdB < v20B);
                const int need = KNN - (int)__popcll(ltm);
                const unsigned long long tiedm = __ballot(vB && sfdB == v20B);
                bool sel;
                if ((int)__popcll(tiedm) == need) {
                    sel = vB && sfdB <= v20B;
                } else {
                    int r = 0;
                    unsigned long long mm = tiedm;
                    while (mm) {
                        const int l = __builtin_ctzll(mm);
                        const unsigned oi = __shfl(sidxB, l, 64);
                        r += (oi < sidxB) ? 1 : 0;
                        mm &= mm - 1;
                    }
                    sel = vB && (sfdB < v20B || (sfdB == v20B && r < need));
                }
                const unsigned long long sm = __ballot(sel);
                if (sel) nbuf[wave][1][mbcnt64(sm)] = sidxB;
            }
        } else {
            // cold path (pathological duplicate clustering): exact fallback
            unsigned fd[16];
            #pragma unroll
            for (int i = 0; i < 16; ++i) {
                const float4 q = pts[i * 64 + lane];
                const float dA = fmaf(n2xA, q.x, fmaf(n2yA, q.y, fmaf(n2zA, q.z, s1A + q.w)));
                fd[i] = flipbits(__float_as_uint(dA));
            }
            fallback20(fd, lane, &nbuf[wave][0][0]);
            #pragma unroll
            for (int i = 0; i < 16; ++i) {
                const float4 q = pts[i * 64 + lane];
                const float dB = fmaf(n2xB, q.x, fmaf(n2yB, q.y, fmaf(n2zB, q.z, s1B + q.w)));
                fd[i] = flipbits(__float_as_uint(dB));
            }
            fallback20(fd, lane, &nbuf[wave][1][0]);
        }

        // EdgeConv, lane = channel, relu/BN deferred; nbuf via packed uint4
        const float mbA = sgn * fmaf(cxA, w3, fmaf(cyA, w4, fmaf(czA, w5, b1l)));
        const float mbB = sgn * fmaf(cxB, w3, fmaf(cyB, w4, fmaf(czB, w5, b1l)));
        const uint4* nbA = (const uint4*)&nbuf[wave][0][0];
        const uint4* nbB = (const uint4*)&nbuf[wave][1][0];
        #pragma unroll
        for (int g = 0; g < 5; ++g) {
            const uint4 iA = nbA[g];
            const uint4 iB = nbB[g];
            {const float4 q = pts[iA.x]; zmax = fmaxf(zmax, fmaf(q.x, w03, fmaf(q.y, w14, fmaf(q.z, w25, mbA))));}
            {const float4 q = pts[iA.y]; zmax = fmaxf(zmax, fmaf(q.x, w03, fmaf(q.y, w14, fmaf(q.z, w25, mbA))));}
            {const float4 q = pts[iA.z]; zmax = fmaxf(zmax, fmaf(q.x, w03, fmaf(q.y, w14, fmaf(q.z, w25, mbA))));}
            {const float4 q = pts[iA.w]; zmax = fmaxf(zmax, fmaf(q.x, w03, fmaf(q.y, w14, fmaf(q.z, w25, mbA))));}
            {const float4 q = pts[iB.x]; zmax = fmaxf(zmax, fmaf(q.x, w03, fmaf(q.y, w14, fmaf(q.z, w25, mbB))));}
            {const float4 q = pts[iB.y]; zmax = fmaxf(zmax, fmaf(q.x, w03, fmaf(q.y, w14, fmaf(q.z, w25, mbB))));}
            {const float4 q = pts[iB.z]; zmax = fmaxf(zmax, fmaf(q.x, w03, fmaf(q.y, w14, fmaf(q.z, w25, mbB))));}
            {const float4 q = pts[iB.w]; zmax = fmaxf(zmax, fmaf(q.x, w03, fmaf(q.y, w14, fmaf(q.z, w25, mbB))));}
        }
    }

    // epilogue: undo sign, relu, BN affine, clamp at 0
    const float r  = fmaxf(sgn * zmax, 0.0f);
    const float h  = fmaf(r, scale, be1l);
    const float cm = fmaxf(h, 0.0f);
    atomicMax(&smax[lane], __float_as_uint(cm));
    __syncthreads();
    if (tid < HH) {
        unsigned* dst = (unsigned*)(acc + ((size_t)b * 448 + t * 64 + tid));
        atomicMax(dst, smax[tid]);
    }
}

// ---------------------------------------------------------------------------
// Kernel B: MLP head, one block (512 threads) per batch row.
// ---------------------------------------------------------------------------
__global__ __launch_bounds__(512) void head_kernel(
    const float* __restrict__ acc,  // [B,448]
    const float* __restrict__ Wa, const float* __restrict__ ba,
    const float* __restrict__ ga, const float* __restrict__ bea,
    const float* __restrict__ Wb, const float* __restrict__ bb,
    const float* __restrict__ gb, const float* __restrict__ beb,
    const float* __restrict__ Wc, const float* __restrict__ bc,
    float* __restrict__ out)        // [B,CLS]
{
    __shared__ float s0[448];
    __shared__ float h1[512];
    __shared__ float h2[256];
    __shared__ float lg[CLS];
    __shared__ float red[2];

    const int b   = blockIdx.x;
    const int tid = threadIdx.x;
    const float inv = 1.0f / sqrtf(1.0f + kEPS);

    if (tid < 448) s0[tid] = acc[(size_t)b * 448 + tid];
    __syncthreads();

    {   // layer a: 448 -> 512
        float s = ba[tid];
        for (int d = 0; d < 448; ++d) s = fmaf(s0[d], Wa[d * 512 + tid], s);
        s = fmaxf(s, 0.0f);
        h1[tid] = fmaf(s, ga[tid] * inv, bea[tid]);
    }
    __syncthreads();
    if (tid < 256) {  // layer b: 512 -> 256
        float s = bb[tid];
        for (int d = 0; d < 512; ++d) s = fmaf(h1[d], Wb[d * 256 + tid], s);
        s = fmaxf(s, 0.0f);
        h2[tid] = fmaf(s, gb[tid] * inv, beb[tid]);
    }
    __syncthreads();
    if (tid < CLS) {  // logits: 256 -> 14
        float s = bc[tid];
        for (int d = 0; d < 256; ++d) s = fmaf(h2[d], Wc[d * CLS + tid], s);
        lg[tid] = s;
    }
    __syncthreads();
    if (tid == 0) {   // log_softmax over 14 classes
        float m = lg[0];
        for (int j = 1; j < CLS; ++j) m = fmaxf(m, lg[j]);
        float ssum = 0.0f;
        for (int j = 0; j < CLS; ++j) ssum += expf(lg[j] - m);
        red[0] = m;
        red[1] = logf(ssum);
    }
    __syncthreads();
    if (tid < CLS) out[(size_t)b * CLS + tid] = lg[tid] - red[0] - red[1];
}

extern "C" void kernel_launch(void* const* d_in, const int* in_sizes, int n_in,
                              void* d_out, int out_size, void* d_ws, size_t ws_size,
                              hipStream_t stream) {
    const float* x   = (const float*)d_in[0];
    // d_in[1] = batch (int64) — unused by the computation
    const float* W1  = (const float*)d_in[2];
    const float* b1  = (const float*)d_in[3];
    const float* g1  = (const float*)d_in[4];
    const float* be1 = (const float*)d_in[5];
    const float* Wa  = (const float*)d_in[6];
    const float* ba  = (const float*)d_in[7];
    const float* ga  = (const float*)d_in[8];
    const float* bea = (const float*)d_in[9];
    const float* Wb  = (const float*)d_in[10];
    const float* bb  = (const float*)d_in[11];
    const float* gb  = (const float*)d_in[12];
    const float* beb = (const float*)d_in[13];
    const float* Wc  = (const float*)d_in[14];
    const float* bc  = (const float*)d_in[15];
    float* out = (float*)d_out;
    float* acc = (float*)d_ws;      // [B,448] accumulator

    hipMemsetAsync(acc, 0, (size_t)BB * 448 * sizeof(float), stream);

    dim3 grid(16, BB, 7);
    knn_edge_kernel<<<grid, 256, 0, stream>>>(x, W1, b1, g1, be1, acc);
    head_kernel<<<BB, 512, 0, stream>>>(acc, Wa, ba, ga, bea,
                                        Wb, bb, gb, beb, Wc, bc, out);
}

// Round 7
// 287.060 us; speedup vs baseline: 2.7202x; 2.7202x over previous
//
#include <hip/hip_runtime.h>

#define BB 32
#define TT 8
#define NN 1024
#define KNN 20
#define HH 64
#define CLS 14

__device__ __constant__ float kEPS = 1e-5f;

// order-preserving flip: float bits -> uint with same total order
__device__ __forceinline__ unsigned flipbits(unsigned u) {
    return u ^ ((unsigned)((int)u >> 31) | 0x80000000u);
}
// inverse of flipbits
__device__ __forceinline__ float unflip(unsigned fu) {
    const unsigned u = (fu & 0x80000000u) ? (fu ^ 0x80000000u) : ~fu;
    return __uint_as_float(u);
}
__device__ __forceinline__ int mbcnt64(unsigned long long m) {
    return (int)__builtin_amdgcn_mbcnt_hi((unsigned)(m >> 32),
            __builtin_amdgcn_mbcnt_lo((unsigned)m, 0u));
}

// Exact iterative extraction fallback (survivor-buffer overflow only; cold).
__device__ __forceinline__ void fallback20(unsigned fd[16], int lane, unsigned* nb) {
    for (int kk = 0; kk < KNN; ++kk) {
        unsigned bv = fd[0];
        int bi = 0;
        #pragma unroll
        for (int i = 1; i < 16; ++i)
            if (fd[i] < bv) { bv = fd[i]; bi = i; }
        unsigned bj = (unsigned)(bi * 64 + lane);
        #pragma unroll
        for (int off = 32; off >= 1; off >>= 1) {
            const unsigned ov = __shfl_xor(bv, off, 64);
            const unsigned oj = __shfl_xor(bj, off, 64);
            if (ov < bv || (ov == bv && oj < bj)) { bv = ov; bj = oj; }
        }
        if (lane == 0) nb[kk] = bj;
        #pragma unroll
        for (int i = 0; i < 16; ++i)
            if (bj == (unsigned)(i * 64 + lane)) fd[i] = 0xFFFFFFFFu;
    }
}

// ---------------------------------------------------------------------------
// Kernel A: per (t, b, 64-point chunk). One wave = 16 query points, ONE at a
// time (R4/R5/R6 lesson: this kernel is latency-bound on serial ballot
// chains; occupancy is the only latency-hider, and the 64-VGPR cliff rules.
// launch_bounds(256,4) pins VGPR=64 — modest spills beat lost waves).
// Per point: float distances -> per-lane min -> 12-step ballot radix on
// flipped lane-mins -> float UB >= d(20) -> ballot-compact survivors into
// LDS (raw float bits + idx) -> 32-step ballot radix over survivor lanes =
// exact v20 -> exact jax top-20 set ({<v20} U lowest-index ties) -> EdgeConv
// with deferred ReLU/BN: track zmax only (weights sign-corrected), apply
// relu/scale/bias/clamp once per thread at the end; uint atomicMax into acc.
// ---------------------------------------------------------------------------
__global__ __launch_bounds__(256, 4) void knn_edge_kernel(
    const float* __restrict__ x,    // [B,T,N,3]
    const float* __restrict__ W1,   // [6,H]
    const float* __restrict__ b1,   // [H]
    const float* __restrict__ g1,   // [H]
    const float* __restrict__ be1,  // [H]
    float* __restrict__ acc)        // [B, 7*H], zero-initialized
{
    __shared__ float4 pts[NN];                      // x, y, z, |p|^2
    __shared__ unsigned long long keybuf[4][64];    // per-wave survivor keys
    __shared__ unsigned nbuf[4][KNN];               // per-wave neighbor indices
    __shared__ unsigned smax[HH];

    const int chunk = blockIdx.x;   // 0..15
    const int b     = blockIdx.y;   // 0..31
    const int t     = blockIdx.z;   // 0..6

    const int tid  = threadIdx.x;
    const int lane = tid & 63;
    const int wave = tid >> 6;

    for (int i = tid; i < NN; i += 256) {
        const float* p = x + (((size_t)b * TT + t) * NN + i) * 3;
        const float px = p[0], py = p[1], pz = p[2];
        pts[i] = make_float4(px, py, pz, px * px + py * py + pz * pz);
    }
    if (tid < HH) smax[tid] = 0u;
    __syncthreads();

    const float w3 = W1[3 * HH + lane], w4 = W1[4 * HH + lane],
                w5 = W1[5 * HH + lane];
    const float b1l   = b1[lane];
    const float scale = g1[lane] / sqrtf(1.0f + kEPS);
    const float be1l  = be1[lane];
    const float sgn = (scale >= 0.0f) ? 1.0f : -1.0f;
    const float w03 = sgn * (W1[0 * HH + lane] - w3),
                w14 = sgn * (W1[1 * HH + lane] - w4),
                w25 = sgn * (W1[2 * HH + lane] - w5);

    float zmax = -3.0e38f;   // max over all edges of sign-corrected pre-activation

    const int n0 = chunk * 64 + wave * 16;
    for (int p = 0; p < 16; ++p) {
        const int n = n0 + p;
        const float* c = x + (((size_t)b * TT + (t + 1)) * NN + n) * 3;
        const float cx = c[0], cy = c[1], cz = c[2];
        const float s1 = cx * cx + cy * cy + cz * cz;
        const float n2x = -2.0f * cx, n2y = -2.0f * cy, n2z = -2.0f * cz;

        // float distances + per-lane min (no per-candidate flips)
        float d[16];
        float mnf = 3.0e38f;
        #pragma unroll
        for (int i = 0; i < 16; ++i) {
            const float4 q = pts[i * 64 + lane];
            d[i] = fmaf(n2x, q.x, fmaf(n2y, q.y, fmaf(n2z, q.z, s1 + q.w)));
            mnf = fminf(mnf, d[i]);
        }
        const unsigned mn = flipbits(__float_as_uint(mnf));

        // 12-step ballot radix on lane-mins: UB >= 20th lane-min >= d(20)
        unsigned pp = 0;
        int krem = 19;
        #pragma unroll
        for (int bit = 31; bit >= 20; --bit) {
            const unsigned long long z = __ballot(((mn ^ pp) >> bit) == 0u);
            const int c0 = (int)__popcll(z);
            if (krem >= c0) { pp |= (1u << bit); krem -= c0; }
        }
        const float ubf = unflip(pp | 0xFFFFFu);   // finite (prefix of a real distance)

        // ballot-compact survivors (d <= ubf) into per-wave LDS key buffer
        int base = 0;
        #pragma unroll
        for (int i = 0; i < 16; ++i) {
            const bool pr = d[i] <= ubf;
            const unsigned long long mk = __ballot(pr);
            if (pr) {
                const int pos = base + mbcnt64(mk);
                if (pos < 64) keybuf[wave][pos] =
                    ((unsigned long long)__float_as_uint(d[i]) << 32)
                    | (unsigned)(i * 64 + lane);
            }
            base += (int)__popcll(mk);
        }

        if (base <= 64) {
            const unsigned long long key = keybuf[wave][lane];
            const bool valid = lane < base;
            const unsigned sfd = valid ? flipbits((unsigned)(key >> 32)) : 0xFFFFFFFFu;
            const unsigned sidx = (unsigned)key & 1023u;

            // exact v20 (rank-19 survivor) via 32-step ballot radix-select
            unsigned v20 = 0;
            int k2 = 19;
            #pragma unroll
            for (int bit = 31; bit >= 0; --bit) {
                const unsigned long long z = __ballot(valid && ((sfd ^ v20) >> bit) == 0u);
                const int c0 = (int)__popcll(z);
                if (k2 >= c0) { v20 |= (1u << bit); k2 -= c0; }
            }

            // exact top-20 set: {fd < v20} U lowest-index ties at v20
            const unsigned long long ltm = __ballot(valid && sfd < v20);
            const int need = KNN - (int)__popcll(ltm);
            const unsigned long long tiedm = __ballot(valid && sfd == v20);
            bool sel;
            if ((int)__popcll(tiedm) == need) {
                sel = valid && sfd <= v20;
            } else {
                int r = 0;
                unsigned long long mm = tiedm;
                while (mm) {
                    const int l = __builtin_ctzll(mm);
                    const unsigned oi = __shfl(sidx, l, 64);
                    r += (oi < sidx) ? 1 : 0;
                    mm &= mm - 1;
                }
                sel = valid && (sfd < v20 || (sfd == v20 && r < need));
            }
            const unsigned long long sm = __ballot(sel);
            if (sel) nbuf[wave][mbcnt64(sm)] = sidx;
        } else {
            // cold path: recompute flipped distances, exact iterative extraction
            unsigned fd[16];
            #pragma unroll
            for (int i = 0; i < 16; ++i) fd[i] = flipbits(__float_as_uint(d[i]));
            fallback20(fd, lane, &nbuf[wave][0]);
        }

        // EdgeConv, lane = channel, relu/BN deferred:
        // z = sgn * (b1 + c·(w3,w4,w5) + n·(w0-w3,w1-w4,w2-w5))
        const float mb = sgn * fmaf(cx, w3, fmaf(cy, w4, fmaf(cz, w5, b1l)));
        #pragma unroll
        for (int kk = 0; kk < KNN; ++kk) {
            const int j = (int)nbuf[wave][kk];     // uniform -> LDS broadcast
            const float4 q = pts[j];
            const float z = fmaf(q.x, w03, fmaf(q.y, w14, fmaf(q.z, w25, mb)));
            zmax = fmaxf(zmax, z);
        }
    }

    // epilogue: undo sign, apply relu, BN affine, clamp at 0
    const float r  = fmaxf(sgn * zmax, 0.0f);
    const float h  = fmaf(r, scale, be1l);
    const float cm = fmaxf(h, 0.0f);
    atomicMax(&smax[lane], __float_as_uint(cm));
    __syncthreads();
    if (tid < HH) {
        unsigned* dst = (unsigned*)(acc + ((size_t)b * 448 + t * 64 + tid));
        atomicMax(dst, smax[tid]);
    }
}

// ---------------------------------------------------------------------------
// Kernel B: MLP head, one block (512 threads) per batch row.
// ---------------------------------------------------------------------------
__global__ __launch_bounds__(512) void head_kernel(
    const float* __restrict__ acc,  // [B,448]
    const float* __restrict__ Wa, const float* __restrict__ ba,
    const float* __restrict__ ga, const float* __restrict__ bea,
    const float* __restrict__ Wb, const float* __restrict__ bb,
    const float* __restrict__ gb, const float* __restrict__ beb,
    const float* __restrict__ Wc, const float* __restrict__ bc,
    float* __restrict__ out)        // [B,CLS]
{
    __shared__ float s0[448];
    __shared__ float h1[512];
    __shared__ float h2[256];
    __shared__ float lg[CLS];
    __shared__ float red[2];

    const int b   = blockIdx.x;
    const int tid = threadIdx.x;
    const float inv = 1.0f / sqrtf(1.0f + kEPS);

    if (tid < 448) s0[tid] = acc[(size_t)b * 448 + tid];
    __syncthreads();

    {   // layer a: 448 -> 512
        float s = ba[tid];
        for (int d = 0; d < 448; ++d) s = fmaf(s0[d], Wa[d * 512 + tid], s);
        s = fmaxf(s, 0.0f);
        h1[tid] = fmaf(s, ga[tid] * inv, bea[tid]);
    }
    __syncthreads();
    if (tid < 256) {  // layer b: 512 -> 256
        float s = bb[tid];
        for (int d = 0; d < 512; ++d) s = fmaf(h1[d], Wb[d * 256 + tid], s);
        s = fmaxf(s, 0.0f);
        h2[tid] = fmaf(s, gb[tid] * inv, beb[tid]);
    }
    __syncthreads();
    if (tid < CLS) {  // logits: 256 -> 14
        float s = bc[tid];
        for (int d = 0; d < 256; ++d) s = fmaf(h2[d], Wc[d * CLS + tid], s);
        lg[tid] = s;
    }
    __syncthreads();
    if (tid == 0) {   // log_softmax over 14 classes
        float m = lg[0];
        for (int j = 1; j < CLS; ++j) m = fmaxf(m, lg[j]);
        float ssum = 0.0f;
        for (int j = 0; j < CLS; ++j) ssum += expf(lg[j] - m);
        red[0] = m;
        red[1] = logf(ssum);
    }
    __syncthreads();
    if (tid < CLS) out[(size_t)b * CLS + tid] = lg[tid] - red[0] - red[1];
}

extern "C" void kernel_launch(void* const* d_in, const int* in_sizes, int n_in,
                              void* d_out, int out_size, void* d_ws, size_t ws_size,
                              hipStream_t stream) {
    const float* x   = (const float*)d_in[0];
    // d_in[1] = batch (int64) — unused by the computation
    const float* W1  = (const float*)d_in[2];
    const float* b1  = (const float*)d_in[3];
    const float* g1  = (const float*)d_in[4];
    const float* be1 = (const float*)d_in[5];
    const float* Wa  = (const float*)d_in[6];
    const float* ba  = (const float*)d_in[7];
    const float* ga  = (const float*)d_in[8];
    const float* bea = (const float*)d_in[9];
    const float* Wb  = (const float*)d_in[10];
    const float* bb  = (const float*)d_in[11];
    const float* gb  = (const float*)d_in[12];
    const float* beb = (const float*)d_in[13];
    const float* Wc  = (const float*)d_in[14];
    const float* bc  = (const float*)d_in[15];
    float* out = (float*)d_out;
    float* acc = (float*)d_ws;      // [B,448] accumulator

    hipMemsetAsync(acc, 0, (size_t)BB * 448 * sizeof(float), stream);

    dim3 grid(16, BB, 7);
    knn_edge_kernel<<<grid, 256, 0, stream>>>(x, W1, b1, g1, be1, acc);
    head_kernel<<<BB, 512, 0, stream>>>(acc, Wa, ba, ga, bea,
                                        Wb, bb, gb, beb, Wc, bc, out);
}